// Round 3
// baseline (319.667 us; speedup 1.0000x reference)
//
#include <hip/hip_runtime.h>
#include <hip/hip_bf16.h>

#define NT 256

__device__ __forceinline__ float2 cmul(float2 a, float2 b){
  return make_float2(a.x*b.x - a.y*b.y, a.x*b.y + a.y*b.x);
}
// XOR-swizzled physical LDS slot: balances wave64 ds_*_b64 to 4 dwords/bank in all 3 phases
__device__ __forceinline__ int phys_of(int idx){
  return idx ^ (((idx >> 4) ^ (idx >> 8)) & 15);
}
// amplitude index for pass p, thread t, register k (k = the 4 bits being operated on)
__device__ __forceinline__ int idx_of(int p, int t, int k){
  if (p == 0) return (t << 4) | k;                               // bits 3..0  (wires 8..11)
  if (p == 1) return ((t & 0xF0) << 4) | (k << 4) | (t & 15);    // bits 7..4  (wires 4..7)
  return (k << 8) | t;                                           // bits 11..8 (wires 0..3)
}

__global__ __launch_bounds__(NT)   // no min-waves hint: LDS caps occupancy anyway; avoid spill-for-occupancy
void qiddm_fused(const float* __restrict__ gx,
                 const float* __restrict__ gcw,
                 const float* __restrict__ gcb,
                 const float* __restrict__ gw1,
                 const float* __restrict__ glw,
                 const float* __restrict__ glb,
                 float* __restrict__ gout)
{
  __shared__ float2 st[4096];        // state; first 4KB doubles as the staged image
  __shared__ float2 tab[6][2][64];   // merged-diagonal phase tables (hi6/lo6 split)
  __shared__ float2 scs[72];         // (cos(th/2), sin(th/2)) per (layer,sublayer,wire)
  __shared__ float  salpha[6][12];   // per-diagonal per-wire angle sums
  __shared__ float  sxr[12];         // current circuit inputs / expvals
  __shared__ float  sred[4][12];     // cross-wave reduction scratch

  const int t = threadIdx.x;
  const int bid = blockIdx.x;
  const int lane = t & 63;
  const int wid = t >> 6;

  // ---------- stage image (1024 f32) into LDS ----------
  float* img = (float*)st;
  {
    float4 u = ((const float4*)gx)[(size_t)bid * 256 + t];
    img[t*4+0] = u.x;
    img[t*4+1] = u.y;
    img[t*4+2] = u.z;
    img[t*4+3] = u.w;
  }
  __syncthreads();

  // ---------- conv 3x3 stride2 pad1 + bias + global average pool -> sxr ----------
  {
    const int oi = t >> 4, oj = t & 15;   // one of the 16x16 output positions per thread
    float p[9];
#pragma unroll
    for (int ki = 0; ki < 3; ki++)
#pragma unroll
      for (int kj = 0; kj < 3; kj++){
        int ri = 2*oi - 1 + ki, cj = 2*oj - 1 + kj;
        p[ki*3+kj] = (ri >= 0 && ri < 32 && cj >= 0 && cj < 32) ? img[ri*32+cj] : 0.0f;
      }
#pragma unroll
    for (int q = 0; q < 12; q++){
      float a = 0.0f;
#pragma unroll
      for (int e = 0; e < 9; e++) a += p[e] * gcw[q*9+e];   // uniform weight loads
#pragma unroll
      for (int off = 32; off > 0; off >>= 1) a += __shfl_down(a, off);
      if (lane == 0) sred[wid][q] = a;
    }
    __syncthreads();
    if (t < 12)
      sxr[t] = gcb[t] + (sred[0][t]+sred[1][t]+sred[2][t]+sred[3][t]) * (1.0f/256.0f);
    __syncthreads();
  }

  // ---------- two sequential circuit blocks ----------
  for (int n = 0; n < 2; n++){
    const float* W = gw1 + n * 216;   // (L=3, 2, 12, 3) per block

    // stage 1: per-wire angle sums (alpha) for the 6 merged diagonals, and RY cos/sin
    // d even = M(i): D_phi(i,l0) * enc [* D_om(i-1,l1) * CZ(r=2) for i>0]
    // d odd  = B(i): D_phi(i,l1) * D_om(i,l0) * CZ(r=1)
    // d = 0 acts on |0> -> global phase -> never applied (tab[0] built but unused)
    if (t < 72){
      int d = t / 12, j = t - d*12;
      int i = d >> 1;
      float a;
      if ((d & 1) == 0){
        a = W[((i*2+0)*12+j)*3+0] + sxr[j];
        if (i > 0) a += W[(((i-1)*2+1)*12+j)*3+2];
      } else {
        a = W[((i*2+1)*12+j)*3+0] + W[((i*2+0)*12+j)*3+2];
      }
      salpha[d][j] = a;
    } else if (t >= 128 && t < 200){
      int e = t - 128;                        // e = (layer*2+sublayer)*12 + wire
      float sv, cv;
      __sincosf(0.5f * W[e*3+1], &sv, &cv);
      scs[e] = make_float2(cv, sv);
    }
    __syncthreads();

    // stage 2: build 6 x (2 x 64) diagonal tables: exp(i * sum_j alpha_j*(b_j - 0.5))
#pragma unroll
    for (int rep = 0; rep < 3; rep++){
      int e = t + rep*256;                    // 768 entries
      int d = e >> 7, half = (e >> 6) & 1, h = e & 63;
      float ph = 0.0f;
#pragma unroll
      for (int jj = 0; jj < 6; jj++)
        ph += salpha[d][half*6+jj] * ((float)((h >> (5-jj)) & 1) - 0.5f);
      float sv, cv;
      __sincosf(ph, &sv, &cv);
      tab[d][half][h] = make_float2(cv, sv);
    }
    __syncthreads();

    // 6 sublayers x 3 fused passes; diagonal d=sl applied at the head of each sublayer (sl>0)
    for (int sl = 0; sl < 6; sl++){
#pragma unroll
      for (int p = 0; p < 3; p++){
        float2 v[16];
        if (sl == 0 && p == 0){
          // fresh |0> state: skip LDS read AND the d=0 diagonal (global phase)
#pragma unroll
          for (int k = 0; k < 16; k++) v[k] = make_float2(0.f, 0.f);
          if (t == 0) v[0] = make_float2(1.f, 0.f);
        } else {
#pragma unroll
          for (int k = 0; k < 16; k++)
            v[k] = st[phys_of(idx_of(p, t, k))];
        }
        if (p == 0 && sl > 0){
          const int r = (sl & 1) ? 1 : 2;     // CZ ring range folded into the diagonal
#pragma unroll
          for (int k = 0; k < 16; k++){
            int idx = idx_of(0, t, k);
            float2 dph = cmul(tab[sl][0][idx >> 6], tab[sl][1][idx & 63]);
            int y = ((idx << r) | (idx >> (12 - r))) & 0xFFF;
            if (__popc(idx & y) & 1){ dph.x = -dph.x; dph.y = -dph.y; }
            v[k] = cmul(v[k], dph);
          }
        }
        // 4 RY gates on local bits 0..3  (wire = 11 - (p*4+lb)); RY is real 2x2
#pragma unroll
        for (int lb = 0; lb < 4; lb++){
          float2 csp = scs[sl*12 + (11 - (p*4 + lb))];
          float c = csp.x, s = csp.y;
#pragma unroll
          for (int k0 = 0; k0 < 16; k0++){
            if (k0 & (1 << lb)) continue;
            int k1 = k0 | (1 << lb);
            float2 a = v[k0], b = v[k1];
            v[k0] = make_float2(c*a.x - s*b.x, c*a.y - s*b.y);
            v[k1] = make_float2(s*a.x + c*b.x, s*a.y + c*b.y);
          }
        }
        if (sl == 5 && p == 2){
          // fused measurement (final diagonal is a pure phase/sign -> dropped).
          // idx = (k<<8)|t: wires 0..3 depend on k only, wires 4..11 on t only.
          float P = 0.f, m0 = 0.f, m1 = 0.f, m2 = 0.f, m3 = 0.f;
#pragma unroll
          for (int k = 0; k < 16; k++){
            float pr = v[k].x*v[k].x + v[k].y*v[k].y;
            P += pr;
            m0 += (k & 8) ? -pr : pr;   // wire 0 (idx bit 11)
            m1 += (k & 4) ? -pr : pr;   // wire 1
            m2 += (k & 2) ? -pr : pr;   // wire 2
            m3 += (k & 1) ? -pr : pr;   // wire 3
          }
#pragma unroll
          for (int q = 0; q < 12; q++){
            float vv;
            if      (q == 0) vv = m0;
            else if (q == 1) vv = m1;
            else if (q == 2) vv = m2;
            else if (q == 3) vv = m3;
            else             vv = ((t >> (11 - q)) & 1) ? -P : P;  // wires 4..11 from t bits
#pragma unroll
            for (int off = 32; off > 0; off >>= 1) vv += __shfl_down(vv, off);
            if (lane == 0) sred[wid][q] = vv;
          }
          __syncthreads();
          if (t < 12) sxr[t] = sred[0][t]+sred[1][t]+sred[2][t]+sred[3][t];
          __syncthreads();
        } else {
#pragma unroll
          for (int k = 0; k < 16; k++)
            st[phys_of(idx_of(p, t, k))] = v[k];
          __syncthreads();
        }
      }
    }
  }

  // ---------- final linear: out[o] = lin_b[o] + sum_j xr[j]*lin_w[o*12+j] ----------
  {
    float xrf[12];
#pragma unroll
    for (int j = 0; j < 12; j++) xrf[j] = sxr[j];
    const int o0 = t * 4;
    float r[4];
#pragma unroll
    for (int o = 0; o < 4; o++){
      int oo = o0 + o;
      float a = glb[oo];
#pragma unroll
      for (int j = 0; j < 12; j++)
        a += xrf[j] * glw[oo*12 + j];
      r[o] = a;
    }
    float4 uo;
    uo.x = r[0]; uo.y = r[1]; uo.z = r[2]; uo.w = r[3];
    ((float4*)gout)[(size_t)bid * 256 + t] = uo;
  }
}

extern "C" void kernel_launch(void* const* d_in, const int* in_sizes, int n_in,
                              void* d_out, int out_size, void* d_ws, size_t ws_size,
                              hipStream_t stream)
{
  (void)n_in; (void)d_ws; (void)ws_size; (void)out_size;
  const float* x  = (const float*)d_in[0];
  const float* cw = (const float*)d_in[1];
  const float* cb = (const float*)d_in[2];
  const float* w1 = (const float*)d_in[3];
  const float* lw = (const float*)d_in[4];
  const float* lb = (const float*)d_in[5];
  float* out = (float*)d_out;
  const int nb = in_sizes[0] / 1024;   // 2048 samples, one workgroup each
  hipLaunchKernelGGL(qiddm_fused, dim3(nb), dim3(NT), 0, stream,
                     x, cw, cb, w1, lw, lb, out);
}

// Round 4
// 243.142 us; speedup vs baseline: 1.3147x; 1.3147x over previous
//
#include <hip/hip_runtime.h>

#define NT 256

typedef float vf2 __attribute__((ext_vector_type(2)));

// (ax*bx - ay*by, ax*by + ay*bx) via 1 pk_mul + 1 pk_fma (swizzle folds into op_sel/neg)
__device__ __forceinline__ vf2 cmulv(vf2 a, vf2 b){
  vf2 br; br.x = -b.y; br.y = b.x;
  return a.x*b + a.y*br;
}
// XOR-swizzled physical LDS slot: balances wave64 ds_*_b64 across banks in all 3 phases
__device__ __forceinline__ int phys_of(int idx){
  return idx ^ (((idx >> 4) ^ (idx >> 8)) & 15);
}
// amplitude index for bit-group g, thread t, register k (k = the 4 bits being operated on)
__device__ __forceinline__ int idx_of(int g, int t, int k){
  if (g == 0) return (t << 4) | k;                               // bits 3..0  (wires 8..11)
  if (g == 1) return ((t & 0xF0) << 4) | (k << 4) | (t & 15);    // bits 7..4  (wires 4..7)
  return (k << 8) | t;                                           // bits 11..8 (wires 0..3)
}

__global__ __launch_bounds__(NT)   // no min-waves hint: LDS caps occupancy; avoid spill-for-occupancy
void qiddm_fused(const float* __restrict__ gx,
                 const float* __restrict__ gcw,
                 const float* __restrict__ gcb,
                 const float* __restrict__ gw1,
                 const float* __restrict__ glw,
                 const float* __restrict__ glb,
                 float* __restrict__ gout)
{
  __shared__ vf2 st[4096];          // state; first 4KB doubles as the staged image
  __shared__ vf2 tab[6][2][64];     // merged-diagonal phase tables (hi6/lo6 split)
  __shared__ vf2 scs[72];           // (cos(th/2), sin(th/2)) per (layer,sublayer,wire)
  __shared__ float salpha[6][12];   // per-diagonal per-wire angle sums
  __shared__ float sxr[12];         // current circuit inputs / expvals
  __shared__ float sred[4][12];     // cross-wave reduction scratch

  const int t = threadIdx.x;
  const int bid = blockIdx.x;
  const int lane = t & 63;
  const int wid = t >> 6;

  // ---------- stage image (1024 f32) into LDS ----------
  float* img = (float*)st;
  {
    float4 u = ((const float4*)gx)[(size_t)bid * 256 + t];
    img[t*4+0] = u.x;
    img[t*4+1] = u.y;
    img[t*4+2] = u.z;
    img[t*4+3] = u.w;
  }
  __syncthreads();

  // ---------- conv 3x3 stride2 pad1 + bias + global average pool -> sxr ----------
  {
    const int oi = t >> 4, oj = t & 15;   // one of the 16x16 output positions per thread
    float p[9];
#pragma unroll
    for (int ki = 0; ki < 3; ki++)
#pragma unroll
      for (int kj = 0; kj < 3; kj++){
        int ri = 2*oi - 1 + ki, cj = 2*oj - 1 + kj;
        p[ki*3+kj] = (ri >= 0 && ri < 32 && cj >= 0 && cj < 32) ? img[ri*32+cj] : 0.0f;
      }
#pragma unroll
    for (int q = 0; q < 12; q++){
      float a = 0.0f;
#pragma unroll
      for (int e = 0; e < 9; e++) a += p[e] * gcw[q*9+e];   // uniform weight loads
#pragma unroll
      for (int off = 32; off > 0; off >>= 1) a += __shfl_down(a, off);
      if (lane == 0) sred[wid][q] = a;
    }
    __syncthreads();
    if (t < 12)
      sxr[t] = gcb[t] + (sred[0][t]+sred[1][t]+sred[2][t]+sred[3][t]) * (1.0f/256.0f);
    __syncthreads();
  }

  // fused-pass schedule: groups rotate; each sublayer's last pass applies the
  // inter-sublayer diagonal then the next sublayer's gates on the same group.
  // 13 passes replace 18: [G0 s0][G1 s0][G2 s0,D1,s1][G0 s1][G1 s1,D2,s2][G2 s2]
  // [G0 s2,D3,s3][G1 s3][G2 s3,D4,s4][G0 s4][G1 s4,D5,s5][G2 s5][G0 s5 +measure]
  constexpr int PGg[13] = {0,1,2,0,1,2,0,1,2,0,1,2,0};
  constexpr int PAs[13] = {0,0,0,1,1,2,2,3,3,4,4,5,5};
  constexpr int PDd[13] = {0,0,1,0,2,0,3,0,4,0,5,0,0};   // 0 = no diagonal

  // ---------- two sequential circuit blocks (each restarts from |0>) ----------
  for (int n = 0; n < 2; n++){
    const float* W = gw1 + n * 216;   // (L=3, 2, 12, 3) per block

    // stage 1: per-wire angle sums for the 6 merged diagonals, and RY cos/sin.
    // d even = D_phi(i,l0)*enc[*D_om(i-1,l1)*CZ(r=2) for i>0]; d odd = D_phi(i,l1)*D_om(i,l0)*CZ(r=1)
    // d = 0 acts on |0> -> global phase -> never applied
    if (t < 72){
      int d = t / 12, j = t - d*12;
      int i = d >> 1;
      float a;
      if ((d & 1) == 0){
        a = W[((i*2+0)*12+j)*3+0] + sxr[j];
        if (i > 0) a += W[(((i-1)*2+1)*12+j)*3+2];
      } else {
        a = W[((i*2+1)*12+j)*3+0] + W[((i*2+0)*12+j)*3+2];
      }
      salpha[d][j] = a;
    } else if (t >= 128 && t < 200){
      int e = t - 128;                        // e = (layer*2+sublayer)*12 + wire
      float sv, cv;
      __sincosf(0.5f * W[e*3+1], &sv, &cv);
      vf2 cs; cs.x = cv; cs.y = sv;
      scs[e] = cs;
    }
    __syncthreads();

    // stage 2: build 6 x (2 x 64) diagonal tables: exp(i * sum_j alpha_j*(b_j - 0.5))
#pragma unroll
    for (int rep = 0; rep < 3; rep++){
      int e = t + rep*256;                    // 768 entries
      int d = e >> 7, half = (e >> 6) & 1, h = e & 63;
      float ph = 0.0f;
#pragma unroll
      for (int jj = 0; jj < 6; jj++)
        ph += salpha[d][half*6+jj] * ((float)((h >> (5-jj)) & 1) - 0.5f);
      float sv, cv;
      __sincosf(ph, &sv, &cv);
      vf2 tv; tv.x = cv; tv.y = sv;
      tab[d][half][h] = tv;
    }
    __syncthreads();

    // ---------- 13 fused passes ----------
#pragma unroll
    for (int p = 0; p < 13; p++){
      const int g = PGg[p];
      vf2 v[16];
      if (p == 0){
        // fresh |0> state: skip the LDS read (and D0: global phase)
#pragma unroll
        for (int k = 0; k < 16; k++){ v[k].x = 0.f; v[k].y = 0.f; }
        if (t == 0) v[0].x = 1.f;
      } else {
#pragma unroll
        for (int k = 0; k < 16; k++)
          v[k] = st[phys_of(idx_of(g, t, k))];
      }

      // 4 RY gates of sublayer PAs[p] on group g (wire = 11 - (g*4+lb)); RY is real 2x2
#pragma unroll
      for (int lb = 0; lb < 4; lb++){
        vf2 cs = scs[PAs[p]*12 + (11 - (g*4 + lb))];
        const float c = cs.x, sn = cs.y;
#pragma unroll
        for (int k0 = 0; k0 < 16; k0++){
          if (k0 & (1 << lb)) continue;
          const int k1 = k0 | (1 << lb);
          vf2 a = v[k0], b = v[k1];
          v[k0] = c*a - sn*b;          // packed fp32
          v[k1] = sn*a + c*b;
        }
      }

      if (PDd[p] > 0){
        // sublayer PAs[p] is now complete everywhere -> apply diagonal d, then
        // the NEXT sublayer's gates on this same group (one LDS round-trip saved)
        const int d = PDd[p];
        const int r = (d & 1) ? 1 : 2;        // CZ ring range folded into the diagonal
#pragma unroll
        for (int k = 0; k < 16; k++){
          int idx = idx_of(g, t, k);
          vf2 dph = cmulv(tab[d][0][idx >> 6], tab[d][1][idx & 63]);
          int y = ((idx << r) | (idx >> (12 - r))) & 0xFFF;
          if (__popc(idx & y) & 1) dph = -dph;
          v[k] = cmulv(v[k], dph);
        }
        const int s2 = d;                     // next sublayer index == d
#pragma unroll
        for (int lb = 0; lb < 4; lb++){
          vf2 cs = scs[s2*12 + (11 - (g*4 + lb))];
          const float c = cs.x, sn = cs.y;
#pragma unroll
          for (int k0 = 0; k0 < 16; k0++){
            if (k0 & (1 << lb)) continue;
            const int k1 = k0 | (1 << lb);
            vf2 a = v[k0], b = v[k1];
            v[k0] = c*a - sn*b;
            v[k1] = sn*a + c*b;
          }
        }
      }

      if (p == 12){
        // fused measurement; g==0 here: idx=(t<<4)|k -> wires 8..11 from k bits,
        // wires 0..7 from t bits. Final diagonal is a pure phase -> dropped.
        float Pp = 0.f, m8 = 0.f, m9 = 0.f, m10 = 0.f, m11 = 0.f;
#pragma unroll
        for (int k = 0; k < 16; k++){
          float pr = v[k].x*v[k].x + v[k].y*v[k].y;
          Pp  += pr;
          m8  += (k & 8) ? -pr : pr;   // wire 8  (idx bit 3)
          m9  += (k & 4) ? -pr : pr;   // wire 9
          m10 += (k & 2) ? -pr : pr;   // wire 10
          m11 += (k & 1) ? -pr : pr;   // wire 11
        }
#pragma unroll
        for (int q = 0; q < 12; q++){
          float vv;
          if (q < 8)        vv = ((t >> (7 - q)) & 1) ? -Pp : Pp;  // wires 0..7 from t bits
          else if (q == 8)  vv = m8;
          else if (q == 9)  vv = m9;
          else if (q == 10) vv = m10;
          else              vv = m11;
#pragma unroll
          for (int off = 32; off > 0; off >>= 1) vv += __shfl_down(vv, off);
          if (lane == 0) sred[wid][q] = vv;
        }
        __syncthreads();
        if (t < 12) sxr[t] = sred[0][t]+sred[1][t]+sred[2][t]+sred[3][t];
        __syncthreads();
      } else {
#pragma unroll
        for (int k = 0; k < 16; k++)
          st[phys_of(idx_of(g, t, k))] = v[k];
        __syncthreads();
      }
    }
  }

  // ---------- final linear: out[o] = lin_b[o] + sum_j xr[j]*lin_w[o*12+j] ----------
  {
    float xrf[12];
#pragma unroll
    for (int j = 0; j < 12; j++) xrf[j] = sxr[j];
    const int o0 = t * 4;
    float r[4];
#pragma unroll
    for (int o = 0; o < 4; o++){
      int oo = o0 + o;
      float a = glb[oo];
#pragma unroll
      for (int j = 0; j < 12; j++)
        a += xrf[j] * glw[oo*12 + j];
      r[o] = a;
    }
    float4 uo;
    uo.x = r[0]; uo.y = r[1]; uo.z = r[2]; uo.w = r[3];
    ((float4*)gout)[(size_t)bid * 256 + t] = uo;
  }
}

extern "C" void kernel_launch(void* const* d_in, const int* in_sizes, int n_in,
                              void* d_out, int out_size, void* d_ws, size_t ws_size,
                              hipStream_t stream)
{
  (void)n_in; (void)d_ws; (void)ws_size; (void)out_size;
  const float* x  = (const float*)d_in[0];
  const float* cw = (const float*)d_in[1];
  const float* cb = (const float*)d_in[2];
  const float* w1 = (const float*)d_in[3];
  const float* lw = (const float*)d_in[4];
  const float* lb = (const float*)d_in[5];
  float* out = (float*)d_out;
  const int nb = in_sizes[0] / 1024;   // 2048 samples, one workgroup each
  hipLaunchKernelGGL(qiddm_fused, dim3(nb), dim3(NT), 0, stream,
                     x, cw, cb, w1, lw, lb, out);
}